// Round 12
// baseline (265.992 us; speedup 1.0000x reference)
//
#include <hip/hip_runtime.h>

#define NNODES 50000
#define NEDGES 800000
#define F 128
#define NREL 8
#define NOUT 1152   // AGG row: 8 rel slices + self slice, fp8
#define NBKT 98     // ceil(50000 / 512) coarse buckets
#define BSH 9       // 512 nodes per bucket
#define SEG 16384   // fixed ebuf segment per bucket (max bucket ~8.5k)
#define NT64 782    // ceil(50000/64) gemm tiles
#define CSR_BLOCKS 196

typedef float f32x4 __attribute__((ext_vector_type(4)));
typedef float f32x2 __attribute__((ext_vector_type(2)));

typedef __attribute__((address_space(3))) void lds_void;
typedef const __attribute__((address_space(1))) void glb_void;
__device__ __forceinline__ void gll16(const void* g, void* l) {
  __builtin_amdgcn_global_load_lds(
      (glb_void*)(unsigned long long)g,
      (lds_void*)(unsigned)(unsigned long long)l, 16, 0, 0);
}

// ========== fused prep: csr-scatter | cvt(fp8) | prepW'(L1) | prepW'(L2) ====
// R26: weights now in GEMM-B layout Wt'[c][kcat] (c=out feat, kcat=r*128+k
// for r<8, 1024+k for self), fp8. Scatter fused back in (bcur zeroed by the
// preceding memset).
#define PREP_CVT   6250    // 50000*128/4 / 256 uints
#define PREP_W     144     // 128*1152/4 / 256 uints per layer
__global__ __launch_bounds__(256)
void k_prep(const float* __restrict__ in_feat, unsigned* __restrict__ feat0,
            const float* __restrict__ W1, const float* __restrict__ W1s,
            unsigned* __restrict__ Wt1,
            const float* __restrict__ W2, const float* __restrict__ W2s,
            unsigned* __restrict__ Wt2,
            const int* __restrict__ src, const int* __restrict__ dst,
            const int* __restrict__ et,
            int* __restrict__ bcur, int* __restrict__ ebuf) {
  const int b = blockIdx.x, t = threadIdx.x;
  if (b < CSR_BLOCKS) {
    // ---- coarse scatter: record = (dst_local<<19)|(src<<3)|et ----
    __shared__ int lhist[NBKT];
    __shared__ int lbase[NBKT];
    if (t < NBKT) lhist[t] = 0;
    __syncthreads();
    int e0 = b * 4096;
    int rec[16], cc[16], lr[16];
#pragma unroll
    for (int i = 0; i < 16; ++i) {
      int e = e0 + t + i * 256;
      if (e < NEDGES) {
        int d = dst[e];
        cc[i] = d >> BSH;
        rec[i] = ((d & 511) << 19) | (src[e] << 3) | et[e];
        lr[i] = atomicAdd(&lhist[cc[i]], 1);
      } else {
        cc[i] = -1;
      }
    }
    __syncthreads();
    if (t < NBKT && lhist[t] > 0) lbase[t] = atomicAdd(&bcur[t], lhist[t]);
    __syncthreads();
#pragma unroll
    for (int i = 0; i < 16; ++i)
      if (cc[i] >= 0) ebuf[cc[i] * SEG + lbase[cc[i]] + lr[i]] = rec[i];
  } else if (b < CSR_BLOCKS + PREP_CVT) {
    int i = (b - CSR_BLOCKS) * 256 + t;   // 1.6M float4 -> uint
    float4 v = ((const float4*)in_feat)[i];
    unsigned pk = 0;
    pk = __builtin_amdgcn_cvt_pk_fp8_f32(v.x, v.y, pk, false);
    pk = __builtin_amdgcn_cvt_pk_fp8_f32(v.z, v.w, pk, true);
    feat0[i] = pk;
  } else {
    int rem = b - CSR_BLOCKS - PREP_CVT;
    int w2 = rem >= PREP_W;
    int idx = (rem - (w2 ? PREP_W : 0)) * 256 + t;  // [0, 36864)
    int c = idx / 288, u = idx - c * 288;           // row c, uint u
    int k0 = u * 4, r = k0 >> 7, kk = k0 & 127;
    const float* Wr = w2 ? W2 : W1;
    const float* Ws = w2 ? W2s : W1s;
    float v0, v1, v2, v3;
    if (r < NREL) {
      v0 = Wr[r * 16384 + (kk + 0) * 128 + c];
      v1 = Wr[r * 16384 + (kk + 1) * 128 + c];
      v2 = Wr[r * 16384 + (kk + 2) * 128 + c];
      v3 = Wr[r * 16384 + (kk + 3) * 128 + c];
    } else {
      v0 = Ws[(kk + 0) * 128 + c];
      v1 = Ws[(kk + 1) * 128 + c];
      v2 = Ws[(kk + 2) * 128 + c];
      v3 = Ws[(kk + 3) * 128 + c];
    }
    unsigned pk = 0;
    pk = __builtin_amdgcn_cvt_pk_fp8_f32(v0, v1, pk, false);
    pk = __builtin_amdgcn_cvt_pk_fp8_f32(v2, v3, pk, true);
    (w2 ? Wt2 : Wt1)[idx] = pk;
  }
}

// ======== fine sort R26: key = (dst_local, et) -> rowptr2[node*8+r] =========
__global__ __launch_bounds__(512)
void k_fsort(const int* __restrict__ ebuf, const int* __restrict__ bcur,
             int* __restrict__ rowptr2, int* __restrict__ edata) {
  __shared__ int cnt[4096];
  __shared__ int pos4[4096];
  __shared__ int ws2[512];
  __shared__ int bc_s;
  const int b = blockIdx.x, t = threadIdx.x;
  // global base = sum_{k<b} bcur[k]
  int myc = (t < NBKT) ? bcur[t] : 0;
  ws2[t] = (t < b) ? myc : 0;
  if (t == b) bc_s = myc;
  __syncthreads();
  for (int off = 1; off < 512; off <<= 1) {
    int x = (t >= off) ? ws2[t - off] : 0;
    __syncthreads();
    ws2[t] += x;
    __syncthreads();
  }
  const int beg = ws2[511];
  const int cntb = bc_s;
  const int sbeg = b * SEG;

#pragma unroll
  for (int i = 0; i < 8; ++i) cnt[t * 8 + i] = 0;
  __syncthreads();
  for (int e = t; e < cntb; e += 512) {
    int rec = ebuf[sbeg + e];
    int key = ((((unsigned)rec) >> 19) << 3) | (rec & 7);
    atomicAdd(&cnt[key], 1);
  }
  __syncthreads();
  int loc[8]; int tot = 0;
#pragma unroll
  for (int i = 0; i < 8; ++i) { loc[i] = tot; tot += cnt[t * 8 + i]; }
  ws2[t] = tot;
  __syncthreads();
  for (int off = 1; off < 512; off <<= 1) {
    int x = (t >= off) ? ws2[t - off] : 0;
    __syncthreads();
    ws2[t] += x;
    __syncthreads();
  }
  int base = beg + ws2[t] - tot;
#pragma unroll
  for (int i = 0; i < 8; ++i) pos4[t * 8 + i] = base + loc[i];
  __syncthreads();
#pragma unroll
  for (int i = 0; i < 8; ++i)
    rowptr2[b * 4096 + t * 8 + i] = pos4[t * 8 + i];
  __syncthreads();
  for (int e = t; e < cntb; e += 512) {
    int rec = ebuf[sbeg + e];
    int key = ((((unsigned)rec) >> 19) << 3) | (rec & 7);
    int p = atomicAdd(&pos4[key], 1);
    edata[p] = (rec >> 3) & 0xFFFF;   // src node index
  }
}

// ========== R26 aggregate-first: AGG[d] = [sum feat[src] per rel | feat[d]] =
// 16 nodes/block, 4 per wave, one 16-lane group per node. Gather source is
// feat0/h1 (6.4MB, L2/L3-resident) - the random gather no longer touches
// HBM. lane s owns feats s*8..s*8+7 (uint2); per rel: batch<=16 edges deep.
// Writes are sequential: 8x128B rel sums (fp8 of f32 sum, exact linearity
// vs ref) + 128B self copy per node.
__global__ __launch_bounds__(256)
void k_aggf(const unsigned char* __restrict__ feat,
            const int* __restrict__ rowptr2, const int* __restrict__ edata,
            unsigned char* __restrict__ agg) {
  const int lane = threadIdx.x & 63;
  const int wv = threadIdx.x >> 6;
  const int G = lane >> 4, s = lane & 15;
  const int node = blockIdx.x * 16 + wv * 4 + G;

  int rp = (s <= 8) ? rowptr2[node * 8 + s] : 0;
  // self slice: straight fp8 copy
  uint2 fv = *(const uint2*)(feat + (size_t)node * F + s * 8);
  *(uint2*)(agg + (size_t)node * NOUT + NREL * F + s * 8) = fv;

#pragma unroll
  for (int r = 0; r < NREL; ++r) {
    int beg = __shfl(rp, r, 16);
    int end = __shfl(rp, r + 1, 16);
    float a[8];
#pragma unroll
    for (int j = 0; j < 8; ++j) a[j] = 0.f;
    for (int base = beg; base < end; base += 16) {
      int cn = end - base; if (cn > 16) cn = 16;
      int my = (base + s < end) ? edata[base + s] : 0;
      uint2 v[16];
#pragma unroll
      for (int k = 0; k < 16; ++k) {
        if (k < cn) {
          int off = __shfl(my, k, 16);
          v[k] = *(const uint2*)(feat + (size_t)off * F + s * 8);
        }
      }
#pragma unroll
      for (int k = 0; k < 16; ++k) {
        if (k < cn) {
          f32x2 l0 = __builtin_amdgcn_cvt_pk_f32_fp8(v[k].x, false);
          f32x2 h0 = __builtin_amdgcn_cvt_pk_f32_fp8(v[k].x, true);
          f32x2 l1 = __builtin_amdgcn_cvt_pk_f32_fp8(v[k].y, false);
          f32x2 h1 = __builtin_amdgcn_cvt_pk_f32_fp8(v[k].y, true);
          a[0] += l0[0]; a[1] += l0[1]; a[2] += h0[0]; a[3] += h0[1];
          a[4] += l1[0]; a[5] += l1[1]; a[6] += h1[0]; a[7] += h1[1];
        }
      }
    }
    unsigned p0 = 0, p1 = 0;
    p0 = __builtin_amdgcn_cvt_pk_fp8_f32(a[0], a[1], p0, false);
    p0 = __builtin_amdgcn_cvt_pk_fp8_f32(a[2], a[3], p0, true);
    p1 = __builtin_amdgcn_cvt_pk_fp8_f32(a[4], a[5], p1, false);
    p1 = __builtin_amdgcn_cvt_pk_fp8_f32(a[6], a[7], p1, true);
    uint2 pk; pk.x = p0; pk.y = p1;
    *(uint2*)(agg + (size_t)node * NOUT + r * F + s * 8) = pk;
  }
}

// ====== R26 GEMM: h[50000][128] = relu(AGG[50000][1152] @ Wt'^T + b) ========
// 64-node x 128-out tile, K=1152 in 9 chunks of 128. 256 thr / 4 waves:
// wave w: mbase=(w&1)*32 (nodes), nbase=(w>>1)*64 (outs). As 8KB, Bs 16KB,
// gll16-staged with the proven 8B-XOR swizzle; fp8 MFMA swapped operands;
// acc accumulates across chunks. Epilogue: bias+relu; hout: fp8 pack via
// R16 sbuf transpose (contiguous 128B row stores). pooled: predicated
// in-lane+shfl reduce over nodes, spread atomics (h2 never materialized).
__global__ __launch_bounds__(256)
void k_gemm(const unsigned char* __restrict__ A,
            const unsigned char* __restrict__ Wt,
            const float* __restrict__ bias, unsigned char* __restrict__ hout,
            float* __restrict__ pooled_p) {
  __shared__ uint4 As[512];    // 64 rows x 8 uint4
  __shared__ uint4 Bs[1024];   // 128 rows x 8 uint4
  const int tid = threadIdx.x;
  const int row0 = blockIdx.x * 64;
  const int lane = tid & 63;
  const int w = tid >> 6;            // 0..3
  const int i16 = lane & 15, q = lane >> 4;
  const int mbase = (w & 1) * 32, nbase = (w >> 1) * 64;

  f32x4 acc[2][4];
#pragma unroll
  for (int a = 0; a < 2; ++a)
#pragma unroll
    for (int b = 0; b < 4; ++b) acc[a][b] = (f32x4)0.f;

  const char* Ab = (const char*)As;
  const char* Bb = (const char*)Bs;

  for (int kc = 0; kc < 9; ++kc) {
    // stage As (nodes): 512 slots, 2/thread; Bs (weights): 1024 slots, 4/thread
#pragma unroll
    for (int i = 0; i < 2; ++i) {
      int L = tid + i * 256;
      int r = L >> 3, c8s = L & 7;
      int c8 = c8s ^ (r & 7);
      int agr = row0 + r; if (agr >= NNODES) agr = NNODES - 1;
      gll16((const void*)(A + (size_t)agr * NOUT + kc * 128 + c8 * 16),
            (void*)&As[L]);
    }
#pragma unroll
    for (int i = 0; i < 4; ++i) {
      int L = tid + i * 256;
      int r = L >> 3, c8s = L & 7;
      int c8 = c8s ^ (r & 7);
      gll16((const void*)(Wt + (size_t)r * NOUT + kc * 128 + c8 * 16),
            (void*)&Bs[L]);
    }
    __syncthreads();

#pragma unroll
    for (int c = 0; c < 4; ++c) {
      const int ch = c * 2 + (q >> 1);
      const int h8 = (q & 1) << 3;
      long af[2], bfr[4];
#pragma unroll
      for (int mi = 0; mi < 2; ++mi) {
        int r = mbase + mi * 16 + i16;
        af[mi] = *(const long*)(Ab + r * 128 + ((ch ^ (r & 7)) << 4) + h8);
      }
#pragma unroll
      for (int ni = 0; ni < 4; ++ni) {
        int r = nbase + ni * 16 + i16;
        bfr[ni] = *(const long*)(Bb + r * 128 + ((ch ^ (r & 7)) << 4) + h8);
      }
#pragma unroll
      for (int mi = 0; mi < 2; ++mi)
#pragma unroll
        for (int ni = 0; ni < 4; ++ni)
          acc[mi][ni] = __builtin_amdgcn_mfma_f32_16x16x32_fp8_fp8(
              bfr[ni], af[mi], acc[mi][ni], 0, 0, 0);
    }
    __syncthreads();   // all waves done with As/Bs before restage
  }

  const int dbase = (nbase >> 2) + q;   // out dword base, [0,32)

  if (hout) {
    // bias + relu + fp8 pack -> sbuf transpose -> contiguous stores
    unsigned pkv[2][4];
#pragma unroll
    for (int mi = 0; mi < 2; ++mi)
#pragma unroll
      for (int ni = 0; ni < 4; ++ni) {
        f32x4 v = acc[mi][ni];
        float4 bb = ((const float4*)bias)[dbase + ni * 4];
        float r0 = fmaxf(v[0] + bb.x, 0.f);
        float r1 = fmaxf(v[1] + bb.y, 0.f);
        float r2 = fmaxf(v[2] + bb.z, 0.f);
        float r3 = fmaxf(v[3] + bb.w, 0.f);
        unsigned pk = 0;
        pk = __builtin_amdgcn_cvt_pk_fp8_f32(r0, r1, pk, false);
        pk = __builtin_amdgcn_cvt_pk_fp8_f32(r2, r3, pk, true);
        pkv[mi][ni] = pk;
      }
    unsigned* sbuf = (unsigned*)As;   // 64 nodes x 32 dwords = 8KB
#pragma unroll
    for (int mi = 0; mi < 2; ++mi) {
      int nl = mbase + mi * 16 + i16;
      int sw = (nl & 7) << 2;
      int vb_ = nl * 32;
#pragma unroll
      for (int ni = 0; ni < 4; ++ni)
        sbuf[vb_ + ((dbase + ni * 4) ^ sw)] = pkv[mi][ni];
    }
    __syncthreads();
#pragma unroll
    for (int k = 0; k < 2; ++k) {
      int nl = k * 32 + (tid >> 3);
      int ch = tid & 7;
      int d0 = (ch * 4) ^ ((nl & 7) << 2);
      uint4 v = *(const uint4*)&sbuf[nl * 32 + d0];
      int row = row0 + nl;
      if (row < NNODES)
        *(uint4*)(hout + (size_t)row * F + ch * 16) = v;
    }
  } else {
    // pooled: bias+relu (invalid nodes zeroed), reduce over nodes, atomics
#pragma unroll
    for (int ni = 0; ni < 4; ++ni) {
      float4 bb = ((const float4*)bias)[dbase + ni * 4];
      float t4[4];
#pragma unroll
      for (int j = 0; j < 4; ++j) t4[j] = 0.f;
#pragma unroll
      for (int mi = 0; mi < 2; ++mi) {
        int row = row0 + mbase + mi * 16 + i16;
        bool ok = row < NNODES;
        f32x4 v = acc[mi][ni];
        t4[0] += ok ? fmaxf(v[0] + bb.x, 0.f) : 0.f;
        t4[1] += ok ? fmaxf(v[1] + bb.y, 0.f) : 0.f;
        t4[2] += ok ? fmaxf(v[2] + bb.z, 0.f) : 0.f;
        t4[3] += ok ? fmaxf(v[3] + bb.w, 0.f) : 0.f;
      }
#pragma unroll
      for (int j = 0; j < 4; ++j) {
        t4[j] += __shfl_xor(t4[j], 1, 64);
        t4[j] += __shfl_xor(t4[j], 2, 64);
        t4[j] += __shfl_xor(t4[j], 4, 64);
        t4[j] += __shfl_xor(t4[j], 8, 64);
      }
      if (i16 == 0) {
        int out0 = (dbase + ni * 4) * 4;
#pragma unroll
        for (int j = 0; j < 4; ++j)
          atomicAdd(&pooled_p[(blockIdx.x & 63) * 128 + out0 + j], t4[j]);
      }
    }
  }
}

// ================== final: reduce 64x128 partials + fc + sigmoid ============
__global__ __launch_bounds__(128)
void k_final(const float* __restrict__ pooled_p, const float* __restrict__ fcw,
             const float* __restrict__ fcb, float* __restrict__ out) {
  __shared__ float s[128];
  int t = threadIdx.x;
  float acc = 0.f;
#pragma unroll 8
  for (int k = 0; k < 64; ++k) acc += pooled_p[k * 128 + t];
  s[t] = acc * (1.0f / (float)NNODES) * fcw[t];
  __syncthreads();
  if (t == 0) {
    float v = 0.f;
    for (int i = 0; i < 128; ++i) v += s[i];
    v += fcb[0];
    out[0] = 1.f / (1.f + expf(-v));
  }
}

// ============================================================================
extern "C" void kernel_launch(void* const* d_in, const int* in_sizes, int n_in,
                              void* d_out, int out_size, void* d_ws, size_t ws_size,
                              hipStream_t stream) {
  const float* in_feat = (const float*)d_in[0];
  const float* W1      = (const float*)d_in[1];
  const float* W1s     = (const float*)d_in[2];
  const float* b1      = (const float*)d_in[3];
  const float* W2      = (const float*)d_in[4];
  const float* W2s     = (const float*)d_in[5];
  const float* b2      = (const float*)d_in[6];
  const float* fcw     = (const float*)d_in[7];
  const float* fcb     = (const float*)d_in[8];
  const int*   src     = (const int*)d_in[9];
  const int*   dst     = (const int*)d_in[10];
  const int*   et      = (const int*)d_in[11];
  float* out = (float*)d_out;

  // Workspace (~76 MB)
  unsigned char* agg  = (unsigned char*)d_ws;             // [50000][1152] fp8
  unsigned char* feat0 = agg + (size_t)NNODES * NOUT;     // [50000][128] fp8
  unsigned char* h1   = feat0 + (size_t)NNODES * F;       // [50000][128] fp8
  unsigned char* Wtp1 = h1 + (size_t)NNODES * F;          // [128][1152] fp8
  unsigned char* Wtp2 = Wtp1 + (size_t)128 * NOUT;        // [128][1152] fp8
  float* pooled_p = (float*)(Wtp2 + (size_t)128 * NOUT);  // [64][128]
  int*   bcur    = (int*)(pooled_p + 64 * 128);           // [NBKT+1]
  int*   rowptr2 = bcur + NBKT + 1;                       // [NBKT*4096]
  int*   ebuf    = rowptr2 + NBKT * 4096;                 // [NBKT*SEG]
  int*   edata   = ebuf + NBKT * SEG;                     // [NEDGES]

  // zero pooled_p + bcur (must precede scatter's atomics -> own dispatch)
  hipMemsetAsync(pooled_p, 0, (64 * 128 + NBKT + 1) * sizeof(float), stream);

  // prep: csr-scatter | feat cvt fp8 | Wt' x2
  k_prep<<<CSR_BLOCKS + PREP_CVT + 2 * PREP_W, 256, 0, stream>>>(
      in_feat, (unsigned*)feat0, W1, W1s, (unsigned*)Wtp1,
      W2, W2s, (unsigned*)Wtp2, src, dst, et, bcur, ebuf);
  k_fsort<<<NBKT, 512, 0, stream>>>(ebuf, bcur, rowptr2, edata);

  // Layer 1: aggregate raw feats per (node,rel) -> AGG, then K=1152 GEMM
  k_aggf<<<NNODES / 16, 256, 0, stream>>>(feat0, rowptr2, edata, agg);
  k_gemm<<<NT64, 256, 0, stream>>>(agg, Wtp1, b1, h1, nullptr);
  // Layer 2: same on h1; pooling fused into GEMM epilogue (no h2)
  k_aggf<<<NNODES / 16, 256, 0, stream>>>(h1, rowptr2, edata, agg);
  k_gemm<<<NT64, 256, 0, stream>>>(agg, Wtp2, b2, nullptr, pooled_p);

  // Reduce partials + fc + sigmoid
  k_final<<<1, 128, 0, stream>>>(pooled_p, fcw, fcb, out);
}

// Round 13
// 198.900 us; speedup vs baseline: 1.3373x; 1.3373x over previous
//
#include <hip/hip_runtime.h>

#define NNODES 50000
#define NEDGES 800000
#define F 128
#define NREL 8
#define NOUT 1152   // 9*128: 8 relations + self-loop
#define NBKT 98     // ceil(50000 / 512) coarse buckets
#define BSH 9       // 512 nodes per bucket
#define SEG 16384   // fixed ebuf segment per bucket (max bucket ~8.5k)
#define NTILES 391  // ceil(50000/128)
#define GEMM_BLOCKS (8 * 9 * 49)   // 3528 (XCD-swizzled)
#define CSR_BLOCKS 196

typedef float f32x4 __attribute__((ext_vector_type(4)));
typedef float f32x2 __attribute__((ext_vector_type(2)));

typedef __attribute__((address_space(3))) void lds_void;
typedef const __attribute__((address_space(1))) void glb_void;
__device__ __forceinline__ void gll16(const void* g, void* l) {
  // async global->LDS, 16B per lane; LDS dest = wave-uniform base + lane*16
  __builtin_amdgcn_global_load_lds(
      (glb_void*)(unsigned long long)g,
      (lds_void*)(unsigned)(unsigned long long)l, 16, 0, 0);
}

// ========== fused prep: zero | cvt(fp8) | prepw(W1) | prepw(W2) =============
#define PREP_ZERO  33
#define PREP_CVT   6250    // 50000*128/4 / 256 uints
#define PREP_W     144     // 1152*128/4 / 256 uints per weight set
__global__ __launch_bounds__(256)
void k_prep(const float* __restrict__ in_feat, unsigned* __restrict__ feat0,
            const float* __restrict__ W1, const float* __restrict__ W1s,
            unsigned* __restrict__ Wt1,
            const float* __restrict__ W2, const float* __restrict__ W2s,
            unsigned* __restrict__ Wt2,
            float* __restrict__ pooled_p, int* __restrict__ bcur) {
  const int b = blockIdx.x, t = threadIdx.x;
  if (b < 32) {
    pooled_p[b * 256 + t] = 0.f;          // 32*256 = 8192 = 64*128
  } else if (b < PREP_ZERO) {
    if (t <= NBKT) bcur[t] = 0;           // bcur[98] (+1 spare)
  } else if (b < PREP_ZERO + PREP_CVT) {
    int i = (b - PREP_ZERO) * 256 + t;    // exactly 1.6M float4 -> uint
    float4 v = ((const float4*)in_feat)[i];
    unsigned pk = 0;
    pk = __builtin_amdgcn_cvt_pk_fp8_f32(v.x, v.y, pk, false);
    pk = __builtin_amdgcn_cvt_pk_fp8_f32(v.z, v.w, pk, true);
    feat0[i] = pk;
  } else {
    int w2 = (b >= PREP_ZERO + PREP_CVT + PREP_W);
    int idx = (b - PREP_ZERO - PREP_CVT - (w2 ? PREP_W : 0)) * 256 + t;
    int n = idx >> 5, k0 = (idx & 31) * 4;   // Wt[n][k0..k0+3]
    int r = n >> 7, c = n & 127;
    const float* Wr = w2 ? W2 : W1;
    const float* Ws = w2 ? W2s : W1s;
    float v0, v1, v2, v3;
    if (r < NREL) {
      v0 = Wr[((size_t)(r * F + k0 + 0)) * F + c];
      v1 = Wr[((size_t)(r * F + k0 + 1)) * F + c];
      v2 = Wr[((size_t)(r * F + k0 + 2)) * F + c];
      v3 = Wr[((size_t)(r * F + k0 + 3)) * F + c];
    } else {
      v0 = Ws[(size_t)(k0 + 0) * F + c];
      v1 = Ws[(size_t)(k0 + 1) * F + c];
      v2 = Ws[(size_t)(k0 + 2) * F + c];
      v3 = Ws[(size_t)(k0 + 3) * F + c];
    }
    unsigned pk = 0;
    pk = __builtin_amdgcn_cvt_pk_fp8_f32(v0, v1, pk, false);
    pk = __builtin_amdgcn_cvt_pk_fp8_f32(v2, v3, pk, true);
    (w2 ? Wt2 : Wt1)[idx] = pk;
  }
}

// ======== fine sort: bucket segment -> CSR (counts from bcur) ===============
__global__ __launch_bounds__(512)
void k_fsort(const int* __restrict__ ebuf, const int* __restrict__ bcur,
             int* __restrict__ rowptr, int* __restrict__ edata) {
  __shared__ int cnt[512];
  __shared__ int pos[512];
  __shared__ int ws2[512];
  __shared__ int bc_s;
  const int b = blockIdx.x, t = threadIdx.x;
  // ---- global base = sum_{k<b} bcur[k] (bcur holds final bucket counts) ----
  int myc = (t < NBKT) ? bcur[t] : 0;
  ws2[t] = (t < b) ? myc : 0;
  if (t == b) bc_s = myc;
  __syncthreads();
  for (int off = 1; off < 512; off <<= 1) {
    int x = (t >= off) ? ws2[t - off] : 0;
    __syncthreads();
    ws2[t] += x;
    __syncthreads();
  }
  const int beg = ws2[511];
  const int cntb = bc_s;
  const int sbeg = b * SEG;  // segment start in ebuf

  cnt[t] = 0;
  __syncthreads();
  for (int e = t; e < cntb; e += 512)
    atomicAdd(&cnt[((unsigned)ebuf[sbeg + e]) >> 19], 1);
  __syncthreads();
  int myn = cnt[t];
  ws2[t] = myn;
  __syncthreads();
  for (int off = 1; off < 512; off <<= 1) {
    int x = (t >= off) ? ws2[t - off] : 0;
    __syncthreads();
    ws2[t] += x;
    __syncthreads();
  }
  pos[t] = ws2[t] - myn;
  __syncthreads();
  int node = (b << BSH) + t;
  if (node < NNODES) rowptr[node] = beg + pos[t];
  if (b == NBKT - 1 && t == 0) rowptr[NNODES] = NEDGES;
  __syncthreads();
  for (int e = t; e < cntb; e += 512) {
    int rec = ebuf[sbeg + e];
    int c = ((unsigned)rec) >> 19;
    int lrank = atomicAdd(&pos[c], 1);
    int srcv = (rec >> 3) & 0xFFFF;
    int etv = rec & 7;
    edata[beg + lrank] = srcv * NOUT + etv * F;  // byte offset in fp8 xrs
  }
}

// ====== GEMM: xrs[50000][1152](fp8) = A[50000][128] @ Wt^T  (fp8 MFMA) ======
// R20: full fp8 datapath. As/Bs 16KB each (LDS 33.5KB -> 4 blocks/CU).
// 8B-granular XOR swizzle; mfma_f32_16x16x32_fp8_fp8, swapped operands.
// Epilogue LDS-transpose stores (R16). doCsr blocks [0,196): CSR scatter.
__global__ __launch_bounds__(512, 8)
void gemm_xrs(const unsigned char* __restrict__ A,
              const unsigned char* __restrict__ Wt,
              unsigned char* __restrict__ xrs, int doCsr,
              const int* __restrict__ src, const int* __restrict__ dst,
              const int* __restrict__ et, int* __restrict__ bcur,
              int* __restrict__ ebuf) {
  __shared__ uint4 As[1024];  // 128 rows x 8 uint4 (fp8), xor-swizzled
  __shared__ uint4 Bs[1024];
  __shared__ int lhist[NBKT];
  __shared__ int lbase[NBKT];
  const int tid = threadIdx.x;

  if (doCsr && blockIdx.x < CSR_BLOCKS) {
    // ---- coarse scatter: record = (dst_local<<19)|(src<<3)|et ----
    if (tid < NBKT) lhist[tid] = 0;
    __syncthreads();
    int e0 = blockIdx.x * 4096;
    int rec[8], cc[8], lr[8];
#pragma unroll
    for (int i = 0; i < 8; ++i) {
      int e = e0 + tid + i * 512;
      if (e < NEDGES) {
        int d = dst[e];
        cc[i] = d >> BSH;
        rec[i] = ((d & 511) << 19) | (src[e] << 3) | et[e];
        lr[i] = atomicAdd(&lhist[cc[i]], 1);
      } else {
        cc[i] = -1;
      }
    }
    __syncthreads();
    if (tid < NBKT && lhist[tid] > 0) lbase[tid] = atomicAdd(&bcur[tid], lhist[tid]);
    __syncthreads();
#pragma unroll
    for (int i = 0; i < 8; ++i)
      if (cc[i] >= 0) ebuf[cc[i] * SEG + lbase[cc[i]] + lr[i]] = rec[i];
    return;
  }

  const int id = blockIdx.x - (doCsr ? CSR_BLOCKS : 0);
  const int x = id & 7, j = id >> 3;
  const int tile = (j / 9) * 8 + x;
  const int cb = j % 9;
  if (tile >= NTILES) return;
  const int row0 = tile * 128;

  const int lane = tid & 63;
  const int w = tid >> 6;           // 0..7
  const int i16 = lane & 15, q = lane >> 4;
  const int mbase = (w & 3) * 32, nbase = (w >> 2) * 64;

  // Stage fp8 tiles via global_load_lds: slot L (r=L>>3, chunk c8s=L&7)
  // receives source chunk c8s ^ (r&7)  (involution matches the read side).
#pragma unroll
  for (int i = 0; i < 2; ++i) {
    int L = tid + i * 512;
    int r = L >> 3, c8s = L & 7;
    int c8 = c8s ^ (r & 7);
    int agr = row0 + r; if (agr >= NNODES) agr = NNODES - 1;
    gll16((const void*)(A + (size_t)agr * F + c8 * 16), (void*)&As[L]);
    gll16((const void*)(Wt + ((size_t)cb * 128 + r) * F + c8 * 16), (void*)&Bs[L]);
  }
  __syncthreads();

  f32x4 acc[2][4];
#pragma unroll
  for (int a = 0; a < 2; ++a)
#pragma unroll
    for (int b = 0; b < 4; ++b) acc[a][b] = (f32x4)0.f;

  const char* Ab = (const char*)As;
  const char* Bb = (const char*)Bs;
#pragma unroll
  for (int c = 0; c < 4; ++c) {
    // lane holds 8 fp8 K-elems: k = c*32 + q*8 .. +7
    const int ch = c * 2 + (q >> 1);   // 16B chunk index of that K-slice
    const int h8 = (q & 1) << 3;       // 8B half within chunk
    long af[2], bfr[4];
#pragma unroll
    for (int mi = 0; mi < 2; ++mi) {
      int r = mbase + mi * 16 + i16;
      af[mi] = *(const long*)(Ab + r * 128 + ((ch ^ (r & 7)) << 4) + h8);
    }
#pragma unroll
    for (int ni = 0; ni < 4; ++ni) {
      int r = nbase + ni * 16 + i16;
      bfr[ni] = *(const long*)(Bb + r * 128 + ((ch ^ (r & 7)) << 4) + h8);
    }
    // Swapped operands: D[m=weight feature][n=node row]
#pragma unroll
    for (int mi = 0; mi < 2; ++mi)
#pragma unroll
      for (int ni = 0; ni < 4; ++ni)
        acc[mi][ni] = __builtin_amdgcn_mfma_f32_16x16x32_fp8_fp8(
            bfr[ni], af[mi], acc[mi][ni], 0, 0, 0);
  }

  // ---- Epilogue with LDS transpose (R16) ----
  unsigned pkv[2][4];
#pragma unroll
  for (int mi = 0; mi < 2; ++mi)
#pragma unroll
    for (int ni = 0; ni < 4; ++ni) {
      f32x4 v = acc[mi][ni];
      unsigned pk = 0;
      pk = __builtin_amdgcn_cvt_pk_fp8_f32(v[0], v[1], pk, false);
      pk = __builtin_amdgcn_cvt_pk_fp8_f32(v[2], v[3], pk, true);
      pkv[mi][ni] = pk;
    }

  __syncthreads();  // all waves done reading As; reuse As as staging (16KB)
  unsigned* sbuf = (unsigned*)As;  // [128 nodes][32 dwords] = 16KB
  {
    const int dbase = (nbase >> 2) + q;
#pragma unroll
    for (int mi = 0; mi < 2; ++mi) {
      int nl = mbase + mi * 16 + i16;
      int sw = (nl & 7) << 2;
      int vb_ = nl * 32;
#pragma unroll
      for (int ni = 0; ni < 4; ++ni)
        sbuf[vb_ + ((dbase + ni * 4) ^ sw)] = pkv[mi][ni];
    }
  }
  __syncthreads();

#pragma unroll
  for (int k = 0; k < 2; ++k) {
    int nl = k * 64 + (tid >> 3);
    int ch = tid & 7;
    int d0 = (ch * 4) ^ ((nl & 7) << 2);
    uint4 v = *(const uint4*)&sbuf[nl * 32 + d0];
    int row = row0 + nl;
    if (row < NNODES)
      *(uint4*)(xrs + (size_t)row * NOUT + cb * 128 + ch * 16) = v;
  }
}

// ========== aggregate: h_next[dst] = relu(sum_e xrs[edata] + self + b) ======
// R27: uint4 gather (halve addresses/edge). 2 nodes per wave (32-lane
// halves); within a half, 4 groups x 8 lanes, each lane owns 16 feats
// (16B uint4 = 1/8 of the 128B row). 4 edges per wave-instr per node,
// depth-8 batches = 32 loads in flight per node. Theory: R25 showed MLP
// is exhausted -> the cap is TA address rate (16 addr/edge at uint2);
// uint4 halves it. Merge across groups: shfl_xor 8,16 (stays in half).
// 6250 blocks x 8 nodes. hout: fp8 uint4 store. pooled_p: LDS-reduce.
__global__ __launch_bounds__(256)
void k_aggregate(const unsigned char* __restrict__ xrs,
                 const int* __restrict__ rowptr, const int* __restrict__ edata,
                 const float* __restrict__ bias, unsigned char* __restrict__ hout,
                 float* __restrict__ pooled_p) {
  __shared__ float red[8][128];
  const int wv = threadIdx.x >> 6;
  const int lane = threadIdx.x & 63;
  const int h = lane >> 5;            // which of the wave's 2 nodes
  const int sl = lane & 31;
  const int g = sl >> 3, s8 = sl & 7; // group (edge slot), 16B chunk owner
  const int node = blockIdx.x * 8 + wv * 2 + h;
  const int beg = rowptr[node], end = rowptr[node + 1];

  float a[16];
#pragma unroll
  for (int j = 0; j < 16; ++j) a[j] = 0.f;

#define ACC4(word, o_) { \
    f32x2 lo_ = __builtin_amdgcn_cvt_pk_f32_fp8((word), false); \
    f32x2 hi_ = __builtin_amdgcn_cvt_pk_f32_fp8((word), true);  \
    a[(o_) + 0] += lo_[0]; a[(o_) + 1] += lo_[1];               \
    a[(o_) + 2] += hi_[0]; a[(o_) + 3] += hi_[1]; }
#define ACC16(v_) { ACC4((v_).x, 0) ACC4((v_).y, 4) ACC4((v_).z, 8) ACC4((v_).w, 12) }

  // self-loop row (r=8), counted once per node by group 0
  if (g == 0) {
    uint4 sv = *(const uint4*)(xrs + (size_t)node * NOUT + NREL * F + s8 * 16);
    ACC16(sv)
  }

  for (int base = beg; base < end; base += 32) {
    int cnt = end - base; if (cnt > 32) cnt = 32;
    int my = (base + sl < end) ? edata[base + sl] : 0;
    int nfull = cnt >> 2, tail = cnt & 3;
    for (int qb = 0; qb < nfull; qb += 8) {
      int nq = nfull - qb; if (nq > 8) nq = 8;
      uint4 v[8];
#pragma unroll
      for (int k = 0; k < 8; ++k) {
        if (k < nq) {
          int off = __shfl(my, 4 * (qb + k) + g, 32);
          v[k] = *(const uint4*)(xrs + (size_t)off + s8 * 16);
        }
      }
#pragma unroll
      for (int k = 0; k < 8; ++k) {
        if (k < nq) ACC16(v[k])
      }
    }
    if (tail) {
      int e = 4 * nfull + g;
      int off = __shfl(my, (e < cnt) ? e : 0, 32);
      if (g < tail) {
        uint4 vv = *(const uint4*)(xrs + (size_t)off + s8 * 16);
        ACC16(vv)
      }
    }
  }

  // merge the 4 group partials within each 32-lane half (xor 8, 16)
#pragma unroll
  for (int j = 0; j < 16; ++j) {
    a[j] += __shfl_xor(a[j], 8, 64);
    a[j] += __shfl_xor(a[j], 16, 64);
  }

  // bias + relu: lane s8 owns feats s8*16 .. +15
#pragma unroll
  for (int i = 0; i < 4; ++i) {
    float4 bb = ((const float4*)bias)[s8 * 4 + i];
    a[i * 4 + 0] = fmaxf(a[i * 4 + 0] + bb.x, 0.f);
    a[i * 4 + 1] = fmaxf(a[i * 4 + 1] + bb.y, 0.f);
    a[i * 4 + 2] = fmaxf(a[i * 4 + 2] + bb.z, 0.f);
    a[i * 4 + 3] = fmaxf(a[i * 4 + 3] + bb.w, 0.f);
  }

  if (hout) {
    if (g == 0) {
      unsigned pk[4];
#pragma unroll
      for (int i = 0; i < 4; ++i) {
        unsigned p = 0;
        p = __builtin_amdgcn_cvt_pk_fp8_f32(a[i * 4 + 0], a[i * 4 + 1], p, false);
        p = __builtin_amdgcn_cvt_pk_fp8_f32(a[i * 4 + 2], a[i * 4 + 3], p, true);
        pk[i] = p;
      }
      *(uint4*)(hout + (size_t)node * F + s8 * 16) =
          make_uint4(pk[0], pk[1], pk[2], pk[3]);
    }
  } else {
    if (g == 0) {
#pragma unroll
      for (int j = 0; j < 16; ++j) red[wv * 2 + h][s8 * 16 + j] = a[j];
    }
    __syncthreads();
    if (threadIdx.x < 128) {
      float sm = 0.f;
#pragma unroll
      for (int r = 0; r < 8; ++r) sm += red[r][threadIdx.x];
      atomicAdd(&pooled_p[(blockIdx.x & 63) * 128 + threadIdx.x], sm);
    }
  }
#undef ACC16
#undef ACC4
}

// ================== final: reduce 64x128 partials + fc + sigmoid ============
__global__ __launch_bounds__(128)
void k_final(const float* __restrict__ pooled_p, const float* __restrict__ fcw,
             const float* __restrict__ fcb, float* __restrict__ out) {
  __shared__ float s[128];
  int t = threadIdx.x;
  float acc = 0.f;
#pragma unroll 8
  for (int k = 0; k < 64; ++k) acc += pooled_p[k * 128 + t];
  s[t] = acc * (1.0f / (float)NNODES) * fcw[t];
  __syncthreads();
  if (t == 0) {
    float v = 0.f;
    for (int i = 0; i < 128; ++i) v += s[i];
    v += fcb[0];
    out[0] = 1.f / (1.f + expf(-v));
  }
}

// ============================================================================
extern "C" void kernel_launch(void* const* d_in, const int* in_sizes, int n_in,
                              void* d_out, int out_size, void* d_ws, size_t ws_size,
                              hipStream_t stream) {
  const float* in_feat = (const float*)d_in[0];
  const float* W1      = (const float*)d_in[1];
  const float* W1s     = (const float*)d_in[2];
  const float* b1      = (const float*)d_in[3];
  const float* W2      = (const float*)d_in[4];
  const float* W2s     = (const float*)d_in[5];
  const float* b2      = (const float*)d_in[6];
  const float* fcw     = (const float*)d_in[7];
  const float* fcb     = (const float*)d_in[8];
  const int*   src     = (const int*)d_in[9];
  const int*   dst     = (const int*)d_in[10];
  const int*   et      = (const int*)d_in[11];
  float* out = (float*)d_out;

  // Workspace (~80 MB)
  unsigned char* xrs = (unsigned char*)d_ws;              // [50000][1152] fp8
  unsigned char* feat0 = xrs + (size_t)NNODES * NOUT;     // [50000][128] fp8
  unsigned char* h1  = feat0 + (size_t)NNODES * F;        // [50000][128] fp8
  unsigned char* Wt1 = h1 + (size_t)NNODES * F;           // [1152][128] fp8
  unsigned char* Wt2 = Wt1 + (size_t)NOUT * F;            // [1152][128] fp8
  float* pooled_p = (float*)(Wt2 + (size_t)NOUT * F);     // [64][128]
  int*   bcur   = (int*)(pooled_p + 64 * 128);            // [NBKT+1]
  int*   rowptr = bcur + NBKT + 1;                        // [NNODES+1]
  int*   ebuf   = rowptr + NNODES + 2;                    // [NBKT*SEG]
  int*   edata  = ebuf + NBKT * SEG;                      // [NEDGES]

  // fused prep: zero(pooled_p,bcur) | feat cvt fp8 | weight prep x2
  k_prep<<<PREP_ZERO + PREP_CVT + 2 * PREP_W, 256, 0, stream>>>(
      in_feat, (unsigned*)feat0, W1, W1s, (unsigned*)Wt1,
      W2, W2s, (unsigned*)Wt2, pooled_p, bcur);

  const int aggBlocks = NNODES / 8;                    // 6250

  // Layer 1 GEMM with CSR-scatter fused (scatter hidden under GEMM)
  gemm_xrs<<<CSR_BLOCKS + GEMM_BLOCKS, 512, 0, stream>>>(
      feat0, Wt1, xrs, 1, src, dst, et, bcur, ebuf);
  k_fsort<<<NBKT, 512, 0, stream>>>(ebuf, bcur, rowptr, edata);
  k_aggregate<<<aggBlocks, 256, 0, stream>>>(xrs, rowptr, edata, b1, h1, nullptr);
  // Layer 2 (pooling fused into aggregate; h2 never materialized)
  gemm_xrs<<<GEMM_BLOCKS, 512, 0, stream>>>(
      h1, Wt2, xrs, 0, src, dst, et, bcur, ebuf);
  k_aggregate<<<aggBlocks, 256, 0, stream>>>(xrs, rowptr, edata, b2, nullptr, pooled_p);

  // Reduce partials + fc + sigmoid
  k_final<<<1, 128, 0, stream>>>(pooled_p, fcw, fcb, out);
}

// Round 14
// 197.372 us; speedup vs baseline: 1.3477x; 1.0077x over previous
//
#include <hip/hip_runtime.h>

#define NNODES 50000
#define NEDGES 800000
#define F 128
#define NREL 8
#define NOUT 1152   // 9*128: 8 relations + self-loop
#define NBKT 98     // ceil(50000 / 512) coarse buckets
#define BSH 9       // 512 nodes per bucket
#define SEG 16384   // fixed ebuf segment per bucket (max bucket ~8.5k)
#define NTILES 391  // ceil(50000/128)
#define GEMM_BLOCKS (8 * 9 * 49)   // 3528 (XCD-swizzled)
#define CSR_BLOCKS 196

typedef float f32x4 __attribute__((ext_vector_type(4)));
typedef float f32x2 __attribute__((ext_vector_type(2)));

typedef __attribute__((address_space(3))) void lds_void;
typedef const __attribute__((address_space(1))) void glb_void;
__device__ __forceinline__ void gll16(const void* g, void* l) {
  // async global->LDS, 16B per lane; LDS dest = wave-uniform base + lane*16
  __builtin_amdgcn_global_load_lds(
      (glb_void*)(unsigned long long)g,
      (lds_void*)(unsigned)(unsigned long long)l, 16, 0, 0);
}

// ====== fused prep R28: csr-scatter | cvt(fp8) | prepw(W1) | prepw(W2) ======
// Scatter fused back in (bcur zeroed by the preceding tiny memset).
#define PREP_CVT   6250    // 50000*128/4 / 256 uints
#define PREP_W     144     // 1152*128/4 / 256 uints per weight set
__global__ __launch_bounds__(256)
void k_prep(const float* __restrict__ in_feat, unsigned* __restrict__ feat0,
            const float* __restrict__ W1, const float* __restrict__ W1s,
            unsigned* __restrict__ Wt1,
            const float* __restrict__ W2, const float* __restrict__ W2s,
            unsigned* __restrict__ Wt2,
            const int* __restrict__ src, const int* __restrict__ dst,
            const int* __restrict__ et,
            int* __restrict__ bcur, int* __restrict__ ebuf) {
  const int b = blockIdx.x, t = threadIdx.x;
  if (b < CSR_BLOCKS) {
    // ---- coarse scatter: record = (dst_local<<19)|(src<<3)|et ----
    __shared__ int lhist[NBKT];
    __shared__ int lbase[NBKT];
    if (t < NBKT) lhist[t] = 0;
    __syncthreads();
    int e0 = b * 4096;
    int rec[16], cc[16], lr[16];
#pragma unroll
    for (int i = 0; i < 16; ++i) {
      int e = e0 + t + i * 256;
      if (e < NEDGES) {
        int d = dst[e];
        cc[i] = d >> BSH;
        rec[i] = ((d & 511) << 19) | (src[e] << 3) | et[e];
        lr[i] = atomicAdd(&lhist[cc[i]], 1);
      } else {
        cc[i] = -1;
      }
    }
    __syncthreads();
    if (t < NBKT && lhist[t] > 0) lbase[t] = atomicAdd(&bcur[t], lhist[t]);
    __syncthreads();
#pragma unroll
    for (int i = 0; i < 16; ++i)
      if (cc[i] >= 0) ebuf[cc[i] * SEG + lbase[cc[i]] + lr[i]] = rec[i];
  } else if (b < CSR_BLOCKS + PREP_CVT) {
    int i = (b - CSR_BLOCKS) * 256 + t;   // exactly 1.6M float4 -> uint
    float4 v = ((const float4*)in_feat)[i];
    unsigned pk = 0;
    pk = __builtin_amdgcn_cvt_pk_fp8_f32(v.x, v.y, pk, false);
    pk = __builtin_amdgcn_cvt_pk_fp8_f32(v.z, v.w, pk, true);
    feat0[i] = pk;
  } else {
    int rem = b - CSR_BLOCKS - PREP_CVT;
    int w2 = rem >= PREP_W;
    int idx = (rem - (w2 ? PREP_W : 0)) * 256 + t;
    int n = idx >> 5, k0 = (idx & 31) * 4;   // Wt[n][k0..k0+3]
    int r = n >> 7, c = n & 127;
    const float* Wr = w2 ? W2 : W1;
    const float* Ws = w2 ? W2s : W1s;
    float v0, v1, v2, v3;
    if (r < NREL) {
      v0 = Wr[((size_t)(r * F + k0 + 0)) * F + c];
      v1 = Wr[((size_t)(r * F + k0 + 1)) * F + c];
      v2 = Wr[((size_t)(r * F + k0 + 2)) * F + c];
      v3 = Wr[((size_t)(r * F + k0 + 3)) * F + c];
    } else {
      v0 = Ws[(size_t)(k0 + 0) * F + c];
      v1 = Ws[(size_t)(k0 + 1) * F + c];
      v2 = Ws[(size_t)(k0 + 2) * F + c];
      v3 = Ws[(size_t)(k0 + 3) * F + c];
    }
    unsigned pk = 0;
    pk = __builtin_amdgcn_cvt_pk_fp8_f32(v0, v1, pk, false);
    pk = __builtin_amdgcn_cvt_pk_fp8_f32(v2, v3, pk, true);
    (w2 ? Wt2 : Wt1)[idx] = pk;
  }
}

// ====== GEMM: xrs[50000][1152](fp8) = A[50000][128] @ Wt^T  (fp8 MFMA) ======
// R20: full fp8 datapath. As/Bs 16KB each (LDS 33.5KB -> 4 blocks/CU).
// 8B-granular XOR swizzle; mfma_f32_16x16x32_fp8_fp8, swapped operands.
// Epilogue LDS-transpose stores (R16).
// R28: doAux blocks [0,98) run the fine sort (bucket segment -> CSR) with
// its LDS overlaid onto As - hides fsort's ~8us under the 3528 gemm blocks.
// (Scatter now lives in k_prep; bcur is final before this launches.)
__global__ __launch_bounds__(512, 8)
void gemm_xrs(const unsigned char* __restrict__ A,
              const unsigned char* __restrict__ Wt,
              unsigned char* __restrict__ xrs, int doAux,
              const int* __restrict__ ebuf, const int* __restrict__ bcur,
              int* __restrict__ rowptr, int* __restrict__ edata) {
  __shared__ uint4 As[1024];  // 128 rows x 8 uint4 (fp8), xor-swizzled
  __shared__ uint4 Bs[1024];
  const int tid = threadIdx.x;

  if (doAux && blockIdx.x < NBKT) {
    // ---- fine sort (R21 body, LDS overlaid onto As: 4x512 ints = 8KB) ----
    int* cnt = (int*)As;
    int* pos = cnt + 512;
    int* ws2 = pos + 512;
    int* bcs = ws2 + 512;
    const int b = blockIdx.x, t = tid;
    int myc = (t < NBKT) ? bcur[t] : 0;
    ws2[t] = (t < b) ? myc : 0;
    if (t == b) *bcs = myc;
    __syncthreads();
    for (int off = 1; off < 512; off <<= 1) {
      int x = (t >= off) ? ws2[t - off] : 0;
      __syncthreads();
      ws2[t] += x;
      __syncthreads();
    }
    const int beg = ws2[511];
    const int cntb = *bcs;
    const int sbeg = b * SEG;

    cnt[t] = 0;
    __syncthreads();
    for (int e = t; e < cntb; e += 512)
      atomicAdd(&cnt[((unsigned)ebuf[sbeg + e]) >> 19], 1);
    __syncthreads();
    int myn = cnt[t];
    ws2[t] = myn;
    __syncthreads();
    for (int off = 1; off < 512; off <<= 1) {
      int x = (t >= off) ? ws2[t - off] : 0;
      __syncthreads();
      ws2[t] += x;
      __syncthreads();
    }
    pos[t] = ws2[t] - myn;
    __syncthreads();
    int node = (b << BSH) + t;
    if (node < NNODES) rowptr[node] = beg + pos[t];
    if (b == NBKT - 1 && t == 0) rowptr[NNODES] = NEDGES;
    __syncthreads();
    for (int e = t; e < cntb; e += 512) {
      int rec = ebuf[sbeg + e];
      int c = ((unsigned)rec) >> 19;
      int lrank = atomicAdd(&pos[c], 1);
      int srcv = (rec >> 3) & 0xFFFF;
      int etv = rec & 7;
      edata[beg + lrank] = srcv * NOUT + etv * F;  // byte offset in fp8 xrs
    }
    return;
  }

  const int id = blockIdx.x - (doAux ? NBKT : 0);
  const int x = id & 7, j = id >> 3;
  const int tile = (j / 9) * 8 + x;
  const int cb = j % 9;
  if (tile >= NTILES) return;
  const int row0 = tile * 128;

  const int lane = tid & 63;
  const int w = tid >> 6;           // 0..7
  const int i16 = lane & 15, q = lane >> 4;
  const int mbase = (w & 3) * 32, nbase = (w >> 2) * 64;

  // Stage fp8 tiles via global_load_lds: slot L (r=L>>3, chunk c8s=L&7)
  // receives source chunk c8s ^ (r&7)  (involution matches the read side).
#pragma unroll
  for (int i = 0; i < 2; ++i) {
    int L = tid + i * 512;
    int r = L >> 3, c8s = L & 7;
    int c8 = c8s ^ (r & 7);
    int agr = row0 + r; if (agr >= NNODES) agr = NNODES - 1;
    gll16((const void*)(A + (size_t)agr * F + c8 * 16), (void*)&As[L]);
    gll16((const void*)(Wt + ((size_t)cb * 128 + r) * F + c8 * 16), (void*)&Bs[L]);
  }
  __syncthreads();

  f32x4 acc[2][4];
#pragma unroll
  for (int a = 0; a < 2; ++a)
#pragma unroll
    for (int b = 0; b < 4; ++b) acc[a][b] = (f32x4)0.f;

  const char* Ab = (const char*)As;
  const char* Bb = (const char*)Bs;
#pragma unroll
  for (int c = 0; c < 4; ++c) {
    // lane holds 8 fp8 K-elems: k = c*32 + q*8 .. +7
    const int ch = c * 2 + (q >> 1);   // 16B chunk index of that K-slice
    const int h8 = (q & 1) << 3;       // 8B half within chunk
    long af[2], bfr[4];
#pragma unroll
    for (int mi = 0; mi < 2; ++mi) {
      int r = mbase + mi * 16 + i16;
      af[mi] = *(const long*)(Ab + r * 128 + ((ch ^ (r & 7)) << 4) + h8);
    }
#pragma unroll
    for (int ni = 0; ni < 4; ++ni) {
      int r = nbase + ni * 16 + i16;
      bfr[ni] = *(const long*)(Bb + r * 128 + ((ch ^ (r & 7)) << 4) + h8);
    }
    // Swapped operands: D[m=weight feature][n=node row]
#pragma unroll
    for (int mi = 0; mi < 2; ++mi)
#pragma unroll
      for (int ni = 0; ni < 4; ++ni)
        acc[mi][ni] = __builtin_amdgcn_mfma_f32_16x16x32_fp8_fp8(
            bfr[ni], af[mi], acc[mi][ni], 0, 0, 0);
  }

  // ---- Epilogue with LDS transpose (R16) ----
  unsigned pkv[2][4];
#pragma unroll
  for (int mi = 0; mi < 2; ++mi)
#pragma unroll
    for (int ni = 0; ni < 4; ++ni) {
      f32x4 v = acc[mi][ni];
      unsigned pk = 0;
      pk = __builtin_amdgcn_cvt_pk_fp8_f32(v[0], v[1], pk, false);
      pk = __builtin_amdgcn_cvt_pk_fp8_f32(v[2], v[3], pk, true);
      pkv[mi][ni] = pk;
    }

  __syncthreads();  // all waves done reading As; reuse As as staging (16KB)
  unsigned* sbuf = (unsigned*)As;  // [128 nodes][32 dwords] = 16KB
  {
    const int dbase = (nbase >> 2) + q;
#pragma unroll
    for (int mi = 0; mi < 2; ++mi) {
      int nl = mbase + mi * 16 + i16;
      int sw = (nl & 7) << 2;
      int vb_ = nl * 32;
#pragma unroll
      for (int ni = 0; ni < 4; ++ni)
        sbuf[vb_ + ((dbase + ni * 4) ^ sw)] = pkv[mi][ni];
    }
  }
  __syncthreads();

#pragma unroll
  for (int k = 0; k < 2; ++k) {
    int nl = k * 64 + (tid >> 3);
    int ch = tid & 7;
    int d0 = (ch * 4) ^ ((nl & 7) << 2);
    uint4 v = *(const uint4*)&sbuf[nl * 32 + d0];
    int row = row0 + nl;
    if (row < NNODES)
      *(uint4*)(xrs + (size_t)row * NOUT + cb * 128 + ch * 16) = v;
  }
}

// ========== aggregate: h_next[dst] = relu(sum_e xrs[edata] + self + b) ======
// R27: uint4 gather (halve addresses/edge). 2 nodes per wave (32-lane
// halves); within a half, 4 groups x 8 lanes, each lane owns 16 feats
// (16B uint4 = 1/8 of the 128B row). 4 edges per wave-instr per node,
// depth-8 batches = 32 loads in flight per node. Merge: shfl_xor 8,16.
// 6250 blocks x 8 nodes. hout: fp8 uint4 store. pooled_p: LDS-reduce.
__global__ __launch_bounds__(256)
void k_aggregate(const unsigned char* __restrict__ xrs,
                 const int* __restrict__ rowptr, const int* __restrict__ edata,
                 const float* __restrict__ bias, unsigned char* __restrict__ hout,
                 float* __restrict__ pooled_p) {
  __shared__ float red[8][128];
  const int wv = threadIdx.x >> 6;
  const int lane = threadIdx.x & 63;
  const int h = lane >> 5;            // which of the wave's 2 nodes
  const int sl = lane & 31;
  const int g = sl >> 3, s8 = sl & 7; // group (edge slot), 16B chunk owner
  const int node = blockIdx.x * 8 + wv * 2 + h;
  const int beg = rowptr[node], end = rowptr[node + 1];

  float a[16];
#pragma unroll
  for (int j = 0; j < 16; ++j) a[j] = 0.f;

#define ACC4(word, o_) { \
    f32x2 lo_ = __builtin_amdgcn_cvt_pk_f32_fp8((word), false); \
    f32x2 hi_ = __builtin_amdgcn_cvt_pk_f32_fp8((word), true);  \
    a[(o_) + 0] += lo_[0]; a[(o_) + 1] += lo_[1];               \
    a[(o_) + 2] += hi_[0]; a[(o_) + 3] += hi_[1]; }
#define ACC16(v_) { ACC4((v_).x, 0) ACC4((v_).y, 4) ACC4((v_).z, 8) ACC4((v_).w, 12) }

  // self-loop row (r=8), counted once per node by group 0
  if (g == 0) {
    uint4 sv = *(const uint4*)(xrs + (size_t)node * NOUT + NREL * F + s8 * 16);
    ACC16(sv)
  }

  for (int base = beg; base < end; base += 32) {
    int cnt = end - base; if (cnt > 32) cnt = 32;
    int my = (base + sl < end) ? edata[base + sl] : 0;
    int nfull = cnt >> 2, tail = cnt & 3;
    for (int qb = 0; qb < nfull; qb += 8) {
      int nq = nfull - qb; if (nq > 8) nq = 8;
      uint4 v[8];
#pragma unroll
      for (int k = 0; k < 8; ++k) {
        if (k < nq) {
          int off = __shfl(my, 4 * (qb + k) + g, 32);
          v[k] = *(const uint4*)(xrs + (size_t)off + s8 * 16);
        }
      }
#pragma unroll
      for (int k = 0; k < 8; ++k) {
        if (k < nq) ACC16(v[k])
      }
    }
    if (tail) {
      int e = 4 * nfull + g;
      int off = __shfl(my, (e < cnt) ? e : 0, 32);
      if (g < tail) {
        uint4 vv = *(const uint4*)(xrs + (size_t)off + s8 * 16);
        ACC16(vv)
      }
    }
  }

  // merge the 4 group partials within each 32-lane half (xor 8, 16)
#pragma unroll
  for (int j = 0; j < 16; ++j) {
    a[j] += __shfl_xor(a[j], 8, 64);
    a[j] += __shfl_xor(a[j], 16, 64);
  }

  // bias + relu: lane s8 owns feats s8*16 .. +15
#pragma unroll
  for (int i = 0; i < 4; ++i) {
    float4 bb = ((const float4*)bias)[s8 * 4 + i];
    a[i * 4 + 0] = fmaxf(a[i * 4 + 0] + bb.x, 0.f);
    a[i * 4 + 1] = fmaxf(a[i * 4 + 1] + bb.y, 0.f);
    a[i * 4 + 2] = fmaxf(a[i * 4 + 2] + bb.z, 0.f);
    a[i * 4 + 3] = fmaxf(a[i * 4 + 3] + bb.w, 0.f);
  }

  if (hout) {
    if (g == 0) {
      unsigned pk[4];
#pragma unroll
      for (int i = 0; i < 4; ++i) {
        unsigned p = 0;
        p = __builtin_amdgcn_cvt_pk_fp8_f32(a[i * 4 + 0], a[i * 4 + 1], p, false);
        p = __builtin_amdgcn_cvt_pk_fp8_f32(a[i * 4 + 2], a[i * 4 + 3], p, true);
        pk[i] = p;
      }
      *(uint4*)(hout + (size_t)node * F + s8 * 16) =
          make_uint4(pk[0], pk[1], pk[2], pk[3]);
    }
  } else {
    if (g == 0) {
#pragma unroll
      for (int j = 0; j < 16; ++j) red[wv * 2 + h][s8 * 16 + j] = a[j];
    }
    __syncthreads();
    if (threadIdx.x < 128) {
      float sm = 0.f;
#pragma unroll
      for (int r = 0; r < 8; ++r) sm += red[r][threadIdx.x];
      atomicAdd(&pooled_p[(blockIdx.x & 63) * 128 + threadIdx.x], sm);
    }
  }
#undef ACC16
#undef ACC4
}

// ================== final: reduce 64x128 partials + fc + sigmoid ============
// R28: parallel tail (shfl tree) instead of thread-0's serial 128-add loop.
__global__ __launch_bounds__(128)
void k_final(const float* __restrict__ pooled_p, const float* __restrict__ fcw,
             const float* __restrict__ fcb, float* __restrict__ out) {
  __shared__ float s[128];
  int t = threadIdx.x;
  float acc = 0.f;
#pragma unroll 8
  for (int k = 0; k < 64; ++k) acc += pooled_p[k * 128 + t];
  s[t] = acc * (1.0f / (float)NNODES) * fcw[t];
  __syncthreads();
  if (t < 64) {
    float x = s[t] + s[t + 64];
    x += __shfl_down(x, 32, 64);
    x += __shfl_down(x, 16, 64);
    x += __shfl_down(x, 8, 64);
    x += __shfl_down(x, 4, 64);
    x += __shfl_down(x, 2, 64);
    x += __shfl_down(x, 1, 64);
    if (t == 0) {
      float v = x + fcb[0];
      out[0] = 1.f / (1.f + expf(-v));
    }
  }
}

// ============================================================================
extern "C" void kernel_launch(void* const* d_in, const int* in_sizes, int n_in,
                              void* d_out, int out_size, void* d_ws, size_t ws_size,
                              hipStream_t stream) {
  const float* in_feat = (const float*)d_in[0];
  const float* W1      = (const float*)d_in[1];
  const float* W1s     = (const float*)d_in[2];
  const float* b1      = (const float*)d_in[3];
  const float* W2      = (const float*)d_in[4];
  const float* W2s     = (const float*)d_in[5];
  const float* b2      = (const float*)d_in[6];
  const float* fcw     = (const float*)d_in[7];
  const float* fcb     = (const float*)d_in[8];
  const int*   src     = (const int*)d_in[9];
  const int*   dst     = (const int*)d_in[10];
  const int*   et      = (const int*)d_in[11];
  float* out = (float*)d_out;

  // Workspace (~80 MB)
  unsigned char* xrs = (unsigned char*)d_ws;              // [50000][1152] fp8
  unsigned char* feat0 = xrs + (size_t)NNODES * NOUT;     // [50000][128] fp8
  unsigned char* h1  = feat0 + (size_t)NNODES * F;        // [50000][128] fp8
  unsigned char* Wt1 = h1 + (size_t)NNODES * F;           // [1152][128] fp8
  unsigned char* Wt2 = Wt1 + (size_t)NOUT * F;            // [1152][128] fp8
  float* pooled_p = (float*)(Wt2 + (size_t)NOUT * F);     // [64][128]
  int*   bcur   = (int*)(pooled_p + 64 * 128);            // [NBKT+1]
  int*   rowptr = bcur + NBKT + 1;                        // [NNODES+1]
  int*   ebuf   = rowptr + NNODES + 2;                    // [NBKT*SEG]
  int*   edata  = ebuf + NBKT * SEG;                      // [NEDGES]

  // zero pooled_p + bcur (must precede scatter's atomics in k_prep)
  hipMemsetAsync(pooled_p, 0, (64 * 128 + NBKT + 1) * sizeof(float), stream);

  // fused prep: csr-scatter | feat cvt fp8 | weight prep x2
  k_prep<<<CSR_BLOCKS + PREP_CVT + 2 * PREP_W, 256, 0, stream>>>(
      in_feat, (unsigned*)feat0, W1, W1s, (unsigned*)Wt1,
      W2, W2s, (unsigned*)Wt2, src, dst, et, bcur, ebuf);

  const int aggBlocks = NNODES / 8;                    // 6250

  // Layer 1 GEMM with fsort fused at grid head (hidden under gemm blocks)
  gemm_xrs<<<NBKT + GEMM_BLOCKS, 512, 0, stream>>>(
      feat0, Wt1, xrs, 1, ebuf, bcur, rowptr, edata);
  k_aggregate<<<aggBlocks, 256, 0, stream>>>(xrs, rowptr, edata, b1, h1, nullptr);
  // Layer 2 (pooling fused into aggregate; h2 never materialized)
  gemm_xrs<<<GEMM_BLOCKS, 512, 0, stream>>>(
      h1, Wt2, xrs, 0, ebuf, bcur, rowptr, edata);
  k_aggregate<<<aggBlocks, 256, 0, stream>>>(xrs, rowptr, edata, b2, nullptr, pooled_p);

  // Reduce partials + fc + sigmoid
  k_final<<<1, 128, 0, stream>>>(pooled_p, fcw, fcb, out);
}